// Round 6
// baseline (248.834 us; speedup 1.0000x reference)
//
#include <hip/hip_runtime.h>
#include <hip/hip_bf16.h>
#include <math.h>

// dtypes for MFMA
typedef __bf16 bf16x8 __attribute__((ext_vector_type(8)));
typedef float  f32x16 __attribute__((ext_vector_type(16)));

// ---- workspace layout (float offsets) ----
// wfrag : 65536 bf16 (fragment-ready W)          [0, 32768) floats
// wlast : 256 fp32 (column 256 of conv_w)        [32768, 33024)
// accA  : [128][256] fp32                        [164096, 196864)
// accX  : [128][256] fp32                        [196864, 229632)
#define WLAST_OFF 32768
#define ACCA_OFF  164096
#define ACCX_OFF  196864

static __device__ __forceinline__ unsigned f2bf_u(float f) {
    unsigned u = __builtin_bit_cast(unsigned, f);
    return (u + 0x7fffu + ((u >> 16) & 1u)) >> 16;                     // RNE
}
// packed bf16 pair via HW cvt (memcpy: __hip_bfloat162 not trivially copyable)
static __device__ __forceinline__ unsigned pkbf(float a, float b) {
    __hip_bfloat162 h = __float22bfloat162_rn(make_float2(a, b));      // a in low 16
    unsigned u; __builtin_memcpy(&u, &h, 4); return u;
}
// swizzle for 128-word LDS rows; write 2-way (free), b128 read <=4-way
static __device__ __forceinline__ int swz(int hwr) {
    return ((hwr >> 2) & 7) << 2;
}

// k_init: fragment-ready bf16 W + wlast + zero accumulators.
// A-frag (32x32x16): lane l holds A[o = ot*32 + (l&31)][k = S*16 + (l>>5)*8 + j].
__global__ void k_init(const float* __restrict__ conv_w, float* __restrict__ ws) {
    int idx = blockIdx.x * 256 + threadIdx.x;       // 0..65535
    int j  = idx & 7;
    int l  = (idx >> 3) & 63;
    int ot = (idx >> 9) & 7;
    int S  = idx >> 12;                             // 0..15
    int o  = ot * 32 + (l & 31);
    int k  = S * 16 + (l >> 5) * 8 + j;
    ((unsigned short*)ws)[idx] = (unsigned short)f2bf_u(conv_w[o * 257 + k]);
    if (idx < 256) ws[WLAST_OFF + idx] = conv_w[idx * 257 + 256];
    ws[ACCA_OFF + idx] = 0.0f;                      // zeroes accA then accX (65536 floats)
}

// k_main: persistent-style — grid 256 (= 1 block/CU). Block owns (image, hw-half),
// loops over 8 hw-tiles of 64. Software pipeline: next tile's global loads issued
// before current tile's MFMA+epilogue. Per-o sums in block-private LDS; atomics
// only once at block end (2 blocks/image contend).
__global__ __launch_bounds__(256, 1)
void k_main(const float* __restrict__ x1, const float* __restrict__ x2,
            float* __restrict__ ws) {
    int half = blockIdx.x;             // hw half: 512
    int xb   = blockIdx.y;             // 0..127
    const float* xp = ((xb < 64) ? x1 : x2) + (size_t)(xb & 63) * (256 * 1024);
    const unsigned short* wfrag = (const unsigned short*)ws;

    int tid = threadIdx.x;
    int l = tid & 63, w = tid >> 6;
    int lw = l & 31, q = l >> 5;
    int hwi = tid & 15, kc = tid >> 4;

    // s_sum[0] doubles as the bf16 staging buffer sx (32 KB fits in its 34.8 KB)
    __shared__ float s_sum[2][256][34];   // [0]=sum attn partials, [1]=sum attn*x
    __shared__ float sd[64][17];          // center-dot partials
    __shared__ float scen[256], swl[256], dotf[64];
    __shared__ float accL[2][256];        // block-private accumulators
    unsigned (*sx)[128] = (unsigned(*)[128])&s_sum[0][0][0];

    scen[tid] = xp[(size_t)tid * 1024 + 528];      // center = (16,16)
    swl[tid]  = ws[WLAST_OFF + tid];
    accL[0][tid] = 0.f; accL[1][tid] = 0.f;

    const float* xbase = xp + (size_t)(kc * 2) * 1024 + half * 512 + hwi * 4;
    float4 xv[16];
    #pragma unroll
    for (int s = 0; s < 8; ++s) {                  // prologue: tile 0 loads
        xv[2 * s]     = *(const float4*)(xbase + (size_t)(32 * s) * 1024);
        xv[2 * s + 1] = *(const float4*)(xbase + (size_t)(32 * s + 1) * 1024);
    }
    __syncthreads();                               // scen/swl/accL visible

    auto loadA = [&](int S, int it) -> bf16x8 {
        return *(const bf16x8*)(wfrag + (size_t)((S * 8 + (w * 2 + it)) * 64 + l) * 8);
    };
    auto loadB = [&](int S, int jt) -> bf16x8 {
        int hwr = jt * 32 + lw;
        int colb = (S * 8 + q * 4) ^ swz(hwr);
        bf16x8 r; __builtin_memcpy(&r, &sx[hwr][colb], 16);
        return r;
    };

    for (int t8 = 0; t8 < 8; ++t8) {
        int hw0 = half * 512 + t8 * 64;

        // ---- convert + center-dot + stage into sx ----
        float dotp[4] = {0.f, 0.f, 0.f, 0.f};
        #pragma unroll
        for (int s = 0; s < 8; ++s) {
            float4 e = xv[2 * s], o4 = xv[2 * s + 1];
            int c = kc * 2 + 32 * s;
            float s0 = scen[c], s1 = scen[c + 1];
            dotp[0] += e.x * s0 + o4.x * s1;
            dotp[1] += e.y * s0 + o4.y * s1;
            dotp[2] += e.z * s0 + o4.z * s1;
            dotp[3] += e.w * s0 + o4.w * s1;
            int col = kc + 16 * s;
            float ee[4] = {e.x, e.y, e.z, e.w};
            float oo[4] = {o4.x, o4.y, o4.z, o4.w};
            #pragma unroll
            for (int ii = 0; ii < 4; ++ii) {
                int j = (hwi + ii) & 3;            // rotate rows (write 2-way max)
                int hwr = hwi * 4 + j;
                sx[hwr][col ^ swz(hwr)] = pkbf(ee[j], oo[j]);
            }
        }
        #pragma unroll
        for (int j = 0; j < 4; ++j) sd[hwi * 4 + j][kc] = dotp[j];

        // ---- software pipeline: issue NEXT tile's loads now ----
        if (t8 < 7) {
            const float* nb = xbase + (t8 + 1) * 64;
            #pragma unroll
            for (int s = 0; s < 8; ++s) {
                xv[2 * s]     = *(const float4*)(nb + (size_t)(32 * s) * 1024);
                xv[2 * s + 1] = *(const float4*)(nb + (size_t)(32 * s + 1) * 1024);
            }
        }
        __syncthreads();                           // B1: sx + sd ready

        if (tid < 64) {                            // wave 0 finalizes dot
            float ssum = 0.f;
            #pragma unroll
            for (int k2 = 0; k2 < 16; ++k2) ssum += sd[tid][k2];
            dotf[tid] = ssum * (1.0f / 256.0f);
        }

        // ---- MFMA: 16 K-steps, A prefetch distance 2 ----
        f32x16 acc[2][2];
        #pragma unroll
        for (int i = 0; i < 2; ++i)
            #pragma unroll
            for (int j = 0; j < 2; ++j)
                #pragma unroll
                for (int e = 0; e < 16; ++e) acc[i][j][e] = 0.0f;

        bf16x8 A0[2], A1[2], A2[2];
        A0[0] = loadA(0, 0); A0[1] = loadA(0, 1);
        A1[0] = loadA(1, 0); A1[1] = loadA(1, 1);
        #pragma unroll
        for (int S = 0; S < 16; ++S) {
            bf16x8 b0 = loadB(S, 0);
            bf16x8 b1 = loadB(S, 1);
            if (S + 2 < 16) { A2[0] = loadA(S + 2, 0); A2[1] = loadA(S + 2, 1); }
            acc[0][0] = __builtin_amdgcn_mfma_f32_32x32x16_bf16(A0[0], b0, acc[0][0], 0, 0, 0);
            acc[0][1] = __builtin_amdgcn_mfma_f32_32x32x16_bf16(A0[0], b1, acc[0][1], 0, 0, 0);
            acc[1][0] = __builtin_amdgcn_mfma_f32_32x32x16_bf16(A0[1], b0, acc[1][0], 0, 0, 0);
            acc[1][1] = __builtin_amdgcn_mfma_f32_32x32x16_bf16(A0[1], b1, acc[1][1], 0, 0, 0);
            A0[0] = A1[0]; A0[1] = A1[1];
            A1[0] = A2[0]; A1[1] = A2[1];
        }
        __syncthreads();                           // B2: sx dead; dotf ready

        // ---- phase 1: sigmoid + x-products -> LDS scratch (overwrites sx) ----
        float dv0 = dotf[lw];
        float dv1 = dotf[32 + lw];
        #pragma unroll
        for (int it = 0; it < 2; ++it) {
            int ob = w * 64 + it * 32;
            #pragma unroll
            for (int r = 0; r < 16; ++r) {
                int row = (r & 3) + 8 * (r >> 2) + 4 * q;   // C/D layout (m74/m101)
                int o = ob + row;
                float wl = swl[o];
                float z0 = acc[it][0][r] + wl * dv0;
                float z1 = acc[it][1][r] + wl * dv1;
                float a0 = __builtin_amdgcn_rcpf(1.0f + __expf(-z0));
                float a1 = __builtin_amdgcn_rcpf(1.0f + __expf(-z1));
                float xv0 = xp[(size_t)o * 1024 + hw0 + lw];        // L2-hot
                float xv1 = xp[(size_t)o * 1024 + hw0 + 32 + lw];
                s_sum[0][o][lw] = a0 + a1;                  // banks lw: conflict-free
                s_sum[1][o][lw] = a0 * xv0 + a1 * xv1;
            }
        }
        __syncthreads();                           // B3: scratch ready

        // ---- phase 2: owner-thread reduce (o = tid), accumulate in LDS ----
        {
            float sa = 0.f, sw2 = 0.f;
            #pragma unroll
            for (int j3 = 0; j3 < 32; ++j3) {
                sa  += s_sum[0][tid][j3];
                sw2 += s_sum[1][tid][j3];
            }
            accL[0][tid] += sa;
            accL[1][tid] += sw2;
        }
        __syncthreads();                           // B4: before next convert
    }

    // block end: one atomic pair per o (2 blocks per image contend)
    atomicAdd(&ws[ACCA_OFF + xb * 256 + tid], accL[0][tid]);
    atomicAdd(&ws[ACCX_OFF + xb * 256 + tid], accL[1][tid]);
}

// out[b,o] = accX0/(accA0+eps) + accX1/(accA1+eps)
__global__ void k_out(const float* __restrict__ ws, float* __restrict__ out) {
    int idx = blockIdx.x * 256 + threadIdx.x;     // b*256 + o
    int b = idx >> 8, o = idx & 255;
    float a0 = ws[ACCA_OFF + b * 256 + o];
    float p0 = ws[ACCX_OFF + b * 256 + o];
    float a1 = ws[ACCA_OFF + (64 + b) * 256 + o];
    float p1 = ws[ACCX_OFF + (64 + b) * 256 + o];
    out[idx] = p0 / (a0 + 1e-8f) + p1 / (a1 + 1e-8f);
}

extern "C" void kernel_launch(void* const* d_in, const int* in_sizes, int n_in,
                              void* d_out, int out_size, void* d_ws, size_t ws_size,
                              hipStream_t stream) {
    const float* x1     = (const float*)d_in[0];
    const float* x2     = (const float*)d_in[1];
    const float* conv_w = (const float*)d_in[2];
    // d_in[3..6] (caLayer params) are dead: softmax over a size-1 axis == 1.
    float* ws  = (float*)d_ws;
    float* out = (float*)d_out;

    k_init<<<256, 256, 0, stream>>>(conv_w, ws);
    k_main<<<dim3(2, 128), 256, 0, stream>>>(x1, x2, ws);
    k_out<<<64, 256, 0, stream>>>(ws, out);
}

// Round 7
// 186.194 us; speedup vs baseline: 1.3364x; 1.3364x over previous
//
#include <hip/hip_runtime.h>
#include <hip/hip_bf16.h>
#include <math.h>

// dtypes for MFMA
typedef __bf16 bf16x8 __attribute__((ext_vector_type(8)));
typedef float  f32x16 __attribute__((ext_vector_type(16)));

// ---- workspace layout (float offsets) ----
// wfrag : 65536 bf16 (fragment-ready W)          [0, 32768)
// wlast : 256 fp32 (column 256 of conv_w)        [32768, 33024)
// cen   : [128][256] fp32 center pixels          [33024, 65792)
// accA  : [128][256] fp32                        [65792, 98560)
// accX  : [128][256] fp32                        [98560, 131328)
#define WLAST_OFF 32768
#define CEN_OFF   33024
#define ACCA_OFF  65792
#define ACCX_OFF  98560

static __device__ __forceinline__ unsigned f2bf_u(float f) {
    unsigned u = __builtin_bit_cast(unsigned, f);
    return (u + 0x7fffu + ((u >> 16) & 1u)) >> 16;                     // RNE
}
// packed bf16 pair via HW cvt (memcpy: __hip_bfloat162 not trivially copyable)
static __device__ __forceinline__ unsigned pkbf(float a, float b) {
    __hip_bfloat162 h = __float22bfloat162_rn(make_float2(a, b));      // a in low 16
    unsigned u; __builtin_memcpy(&u, &h, 4); return u;
}

// DPP cross-lane add (all-VALU, no LDS pipe)
template<int CTRL, int RM>
static __device__ __forceinline__ float dpp_add(float x) {
    int yi = __builtin_amdgcn_update_dpp(0, __builtin_bit_cast(int, x), CTRL, RM, 0xF, true);
    return x + __builtin_bit_cast(float, yi);
}
// 32-lane (half-wave) sum; valid in lanes 16-31 / 48-63; lane 31/63 used.
static __device__ __forceinline__ float red32(float x) {
    x = dpp_add<0x121, 0xF>(x);   // row_ror:1
    x = dpp_add<0x122, 0xF>(x);   // row_ror:2
    x = dpp_add<0x124, 0xF>(x);   // row_ror:4
    x = dpp_add<0x128, 0xF>(x);   // row_ror:8
    x = dpp_add<0x142, 0xA>(x);   // row_bcast15 into rows 1,3
    return x;
}

// swizzle for 128-word LDS rows; write 2-way (free), b128 read <=4-way
static __device__ __forceinline__ int swz(int hwr) {
    return ((hwr >> 2) & 7) << 2;
}

// k_init: fragment-ready bf16 W + wlast + center extraction + zero accumulators.
// A-frag (32x32x16): lane l holds A[o = ot*32 + (l&31)][k = S*16 + (l>>5)*8 + j].
__global__ void k_init(const float* __restrict__ x1, const float* __restrict__ x2,
                       const float* __restrict__ conv_w, float* __restrict__ ws) {
    int bk = blockIdx.x;
    int tid = threadIdx.x;
    if (bk < 256) {
        int idx = bk * 256 + tid;                   // 0..65535
        int j  = idx & 7;
        int l  = (idx >> 3) & 63;
        int ot = (idx >> 9) & 7;
        int S  = idx >> 12;                         // 0..15
        int o  = ot * 32 + (l & 31);
        int k  = S * 16 + (l >> 5) * 8 + j;
        ((unsigned short*)ws)[idx] = (unsigned short)f2bf_u(conv_w[o * 257 + k]);
        if (idx < 256) ws[WLAST_OFF + idx] = conv_w[idx * 257 + 256];
        ws[ACCA_OFF + idx] = 0.0f;                  // zeroes accA then accX (65536 floats)
    } else {
        int xb = bk - 256;                          // 0..127: extract centers
        const float* xp = ((xb < 64) ? x1 : x2) + (size_t)(xb & 63) * (256 * 1024);
        ws[CEN_OFF + xb * 256 + tid] = xp[(size_t)tid * 1024 + 528];   // (16,16)
    }
}

// k_main: one block = one image x one 64-hw tile, all 256 o, full K=256.
// One-shot staging (max MLP), fused center-dot, bf16 MFMA GEMM, sigmoid,
// epilogue x re-read from the staged LDS tile (NO global re-reads), DPP
// reductions -> global atomics.
__global__ __launch_bounds__(256)
void k_main(const float* __restrict__ x1, const float* __restrict__ x2,
            float* __restrict__ ws) {
    int bx = blockIdx.x;               // hw tile: 16 x 64
    int xb = blockIdx.y;               // 0..127
    const float* xp = ((xb < 64) ? x1 : x2) + (size_t)(xb & 63) * (256 * 1024);
    const unsigned short* wfrag = (const unsigned short*)ws;
    float* accA = ws + ACCA_OFF + xb * 256;
    float* accX = ws + ACCX_OFF + xb * 256;
    int hw0 = bx * 64;

    int tid = threadIdx.x;
    int l = tid & 63, w = tid >> 6;
    int lw = l & 31, q = l >> 5;

    __shared__ unsigned sx[64][128];   // 32 KB: [hw][kword] swizzled, whole K=256
    __shared__ float sd[64][17];       // dot partials
    __shared__ float scen[256];
    __shared__ float swl[256];
    __shared__ float dotf[64];

    int hwi = tid & 15, kc = tid >> 4; // thread: hw hwi*4..+3, channels {2kc,2kc+1}+32s

    // ---- issue ALL X loads up front (16 independent dwordx4) ----
    const float* xst = xp + (size_t)(kc * 2) * 1024 + hw0 + hwi * 4;
    float4 xv[16];
    #pragma unroll
    for (int s = 0; s < 8; ++s) {
        xv[2 * s]     = *(const float4*)(xst + (size_t)(32 * s) * 1024);
        xv[2 * s + 1] = *(const float4*)(xst + (size_t)(32 * s + 1) * 1024);
    }
    scen[tid] = ws[CEN_OFF + xb * 256 + tid];      // coalesced (precomputed)
    swl[tid]  = ws[WLAST_OFF + tid];
    __syncthreads();                               // scen/swl visible

    // ---- convert + LDS write + center-dot ----
    float dotp[4] = {0.f, 0.f, 0.f, 0.f};
    #pragma unroll
    for (int s = 0; s < 8; ++s) {
        float4 e = xv[2 * s], o4 = xv[2 * s + 1];
        int c = kc * 2 + 32 * s;
        float s0 = scen[c], s1 = scen[c + 1];
        dotp[0] += e.x * s0 + o4.x * s1;
        dotp[1] += e.y * s0 + o4.y * s1;
        dotp[2] += e.z * s0 + o4.z * s1;
        dotp[3] += e.w * s0 + o4.w * s1;
        int col = kc + 16 * s;
        float ee[4] = {e.x, e.y, e.z, e.w};
        float oo[4] = {o4.x, o4.y, o4.z, o4.w};
        #pragma unroll
        for (int j = 0; j < 4; ++j) {
            int jj = (hwi + j) & 3;                // rotate rows (write 2-way max)
            int hwr = hwi * 4 + jj;
            sx[hwr][col ^ swz(hwr)] = pkbf(ee[jj], oo[jj]);
        }
    }
    #pragma unroll
    for (int j = 0; j < 4; ++j) sd[hwi * 4 + j][kc] = dotp[j];
    __syncthreads();                               // B1: sx + sd ready

    if (tid < 64) {                                // wave 0 finalizes dot
        float ssum = 0.f;
        #pragma unroll
        for (int k2 = 0; k2 < 16; ++k2) ssum += sd[tid][k2];
        dotf[tid] = ssum * (1.0f / 256.0f);
    }

    // ---- MFMA: 16 K-steps, no barriers, A prefetch distance 2 ----
    f32x16 acc[2][2];                  // [it: o 32-sub][jt: hw 32-sub]
    #pragma unroll
    for (int i = 0; i < 2; ++i)
        #pragma unroll
        for (int j = 0; j < 2; ++j)
            #pragma unroll
            for (int e = 0; e < 16; ++e) acc[i][j][e] = 0.0f;

    auto loadA = [&](int S, int it) -> bf16x8 {
        return *(const bf16x8*)(wfrag + (size_t)((S * 8 + (w * 2 + it)) * 64 + l) * 8);
    };
    auto loadB = [&](int S, int jt) -> bf16x8 {
        int hwr = jt * 32 + lw;
        int colb = (S * 8 + q * 4) ^ swz(hwr);
        bf16x8 r; __builtin_memcpy(&r, &sx[hwr][colb], 16);
        return r;
    };

    bf16x8 A0[2], A1[2], A2[2];
    A0[0] = loadA(0, 0); A0[1] = loadA(0, 1);
    A1[0] = loadA(1, 0); A1[1] = loadA(1, 1);
    #pragma unroll
    for (int S = 0; S < 16; ++S) {
        bf16x8 b0 = loadB(S, 0);
        bf16x8 b1 = loadB(S, 1);
        if (S + 2 < 16) { A2[0] = loadA(S + 2, 0); A2[1] = loadA(S + 2, 1); }
        acc[0][0] = __builtin_amdgcn_mfma_f32_32x32x16_bf16(A0[0], b0, acc[0][0], 0, 0, 0);
        acc[0][1] = __builtin_amdgcn_mfma_f32_32x32x16_bf16(A0[0], b1, acc[0][1], 0, 0, 0);
        acc[1][0] = __builtin_amdgcn_mfma_f32_32x32x16_bf16(A0[1], b0, acc[1][0], 0, 0, 0);
        acc[1][1] = __builtin_amdgcn_mfma_f32_32x32x16_bf16(A0[1], b1, acc[1][1], 0, 0, 0);
        A0[0] = A1[0]; A0[1] = A1[1];
        A1[0] = A2[0]; A1[1] = A2[1];
    }
    __syncthreads();                               // B2: dotf ready, sx intact

    // ---- epilogue: z += wlast*dot; sigmoid; x from LDS (bf16); DPP reduce ----
    float dv0 = dotf[lw];
    float dv1 = dotf[32 + lw];
    #pragma unroll
    for (int it = 0; it < 2; ++it) {
        int ob = w * 64 + it * 32;
        #pragma unroll
        for (int r = 0; r < 16; ++r) {
            int row = (r & 3) + 8 * (r >> 2) + 4 * q;   // C/D layout (m74/m101)
            int o = ob + row;
            float wl = swl[o];
            float z0 = acc[it][0][r] + wl * dv0;
            float z1 = acc[it][1][r] + wl * dv1;
            float a0 = __builtin_amdgcn_rcpf(1.0f + __expf(-z0));
            float a1 = __builtin_amdgcn_rcpf(1.0f + __expf(-z1));
            // x[o][hw0 + jt*32 + lw] from the staged bf16 tile (no global traffic)
            int col = o >> 1;
            unsigned w0 = sx[lw][col ^ swz(lw)];
            unsigned w1 = sx[32 + lw][col ^ swz(32 + lw)];
            float xv0, xv1;
            if (o & 1) {
                xv0 = __builtin_bit_cast(float, w0 & 0xffff0000u);
                xv1 = __builtin_bit_cast(float, w1 & 0xffff0000u);
            } else {
                xv0 = __builtin_bit_cast(float, w0 << 16);
                xv1 = __builtin_bit_cast(float, w1 << 16);
            }
            float sA = red32(a0 + a1);
            float sX = red32(a0 * xv0 + a1 * xv1);
            if (lw == 31) {                             // lanes 31,63 hold sums
                atomicAdd(&accA[o], sA);
                atomicAdd(&accX[o], sX);
            }
        }
    }
}

// out[b,o] = accX0/(accA0+eps) + accX1/(accA1+eps)
__global__ void k_out(const float* __restrict__ ws, float* __restrict__ out) {
    int idx = blockIdx.x * 256 + threadIdx.x;     // b*256 + o
    int b = idx >> 8, o = idx & 255;
    float a0 = ws[ACCA_OFF + b * 256 + o];
    float p0 = ws[ACCX_OFF + b * 256 + o];
    float a1 = ws[ACCA_OFF + (64 + b) * 256 + o];
    float p1 = ws[ACCX_OFF + (64 + b) * 256 + o];
    out[idx] = p0 / (a0 + 1e-8f) + p1 / (a1 + 1e-8f);
}

extern "C" void kernel_launch(void* const* d_in, const int* in_sizes, int n_in,
                              void* d_out, int out_size, void* d_ws, size_t ws_size,
                              hipStream_t stream) {
    const float* x1     = (const float*)d_in[0];
    const float* x2     = (const float*)d_in[1];
    const float* conv_w = (const float*)d_in[2];
    // d_in[3..6] (caLayer params) are dead: softmax over a size-1 axis == 1.
    float* ws  = (float*)d_ws;
    float* out = (float*)d_out;

    k_init<<<384, 256, 0, stream>>>(x1, x2, conv_w, ws);
    k_main<<<dim3(16, 128), 256, 0, stream>>>(x1, x2, ws);
    k_out<<<64, 256, 0, stream>>>(ws, out);
}

// Round 8
// 184.336 us; speedup vs baseline: 1.3499x; 1.0101x over previous
//
#include <hip/hip_runtime.h>
#include <hip/hip_bf16.h>
#include <math.h>

// dtypes for MFMA
typedef __bf16 bf16x8 __attribute__((ext_vector_type(8)));
typedef float  f32x16 __attribute__((ext_vector_type(16)));

// ---- workspace layout (float offsets) ----
// wfrag : 65536 bf16 (fragment-ready W)          [0, 32768)
// wlast : 256 fp32 (column 256 of conv_w)        [32768, 33024)
// cen   : [128][256] fp32 center pixels          [33024, 65792)
// accA  : [128][256] fp32                        [65792, 98560)
// accX  : [128][256] fp32                        [98560, 131328)
#define WLAST_OFF 32768
#define CEN_OFF   33024
#define ACCA_OFF  65792
#define ACCX_OFF  98560

static __device__ __forceinline__ unsigned f2bf_u(float f) {
    unsigned u = __builtin_bit_cast(unsigned, f);
    return (u + 0x7fffu + ((u >> 16) & 1u)) >> 16;                     // RNE
}
// packed bf16 pair via HW cvt (memcpy: __hip_bfloat162 not trivially copyable)
static __device__ __forceinline__ unsigned pkbf(float a, float b) {
    __hip_bfloat162 h = __float22bfloat162_rn(make_float2(a, b));      // a in low 16
    unsigned u; __builtin_memcpy(&u, &h, 4); return u;
}

// DPP cross-lane add (all-VALU, no LDS pipe)
template<int CTRL, int RM>
static __device__ __forceinline__ float dpp_add(float x) {
    int yi = __builtin_amdgcn_update_dpp(0, __builtin_bit_cast(int, x), CTRL, RM, 0xF, true);
    return x + __builtin_bit_cast(float, yi);
}
// 32-lane (half-wave) sum; valid in lanes 16-31 / 48-63; lane 31/63 used.
static __device__ __forceinline__ float red32(float x) {
    x = dpp_add<0x121, 0xF>(x);   // row_ror:1
    x = dpp_add<0x122, 0xF>(x);   // row_ror:2
    x = dpp_add<0x124, 0xF>(x);   // row_ror:4
    x = dpp_add<0x128, 0xF>(x);   // row_ror:8
    x = dpp_add<0x142, 0xA>(x);   // row_bcast15 into rows 1,3
    return x;
}

// swizzle for 128-word LDS rows; write 2-way (free), b128 read <=4-way
static __device__ __forceinline__ int swz(int hwr) {
    return ((hwr >> 2) & 7) << 2;
}

// k_init: fragment-ready bf16 W + wlast + center extraction + zero accumulators.
// A-frag (32x32x16): lane l holds A[o = ot*32 + (l&31)][k = S*16 + (l>>5)*8 + j].
__global__ void k_init(const float* __restrict__ x1, const float* __restrict__ x2,
                       const float* __restrict__ conv_w, float* __restrict__ ws) {
    int bk = blockIdx.x;
    int tid = threadIdx.x;
    if (bk < 256) {
        int idx = bk * 256 + tid;                   // 0..65535
        int j  = idx & 7;
        int l  = (idx >> 3) & 63;
        int ot = (idx >> 9) & 7;
        int S  = idx >> 12;                         // 0..15
        int o  = ot * 32 + (l & 31);
        int k  = S * 16 + (l >> 5) * 8 + j;
        ((unsigned short*)ws)[idx] = (unsigned short)f2bf_u(conv_w[o * 257 + k]);
        if (idx < 256) ws[WLAST_OFF + idx] = conv_w[idx * 257 + 256];
        ws[ACCA_OFF + idx] = 0.0f;                  // zeroes accA then accX (65536 floats)
    } else {
        int xb = bk - 256;                          // 0..127: extract centers
        const float* xp = ((xb < 64) ? x1 : x2) + (size_t)(xb & 63) * (256 * 1024);
        ws[CEN_OFF + xb * 256 + tid] = xp[(size_t)tid * 1024 + 528];   // (16,16)
    }
}

// k_main: one block = one image x one 64-hw tile, all 256 o, full K=256.
// One-shot staging with FORCED load clustering (sched_barrier + VGPR headroom),
// fused center-dot, bf16 MFMA GEMM, sigmoid, epilogue x from staged LDS tile,
// DPP reductions -> global atomics.
__global__ __launch_bounds__(256, 4)   // 4 waves/EU -> VGPR cap 128: xv[16] stays live
void k_main(const float* __restrict__ x1, const float* __restrict__ x2,
            float* __restrict__ ws) {
    int bx = blockIdx.x;               // hw tile: 16 x 64
    int xb = blockIdx.y;               // 0..127
    const float* xp = ((xb < 64) ? x1 : x2) + (size_t)(xb & 63) * (256 * 1024);
    const unsigned short* wfrag = (const unsigned short*)ws;
    float* accA = ws + ACCA_OFF + xb * 256;
    float* accX = ws + ACCX_OFF + xb * 256;
    int hw0 = bx * 64;

    int tid = threadIdx.x;
    int l = tid & 63, w = tid >> 6;
    int lw = l & 31, q = l >> 5;

    __shared__ unsigned sx[64][128];   // 32 KB: [hw][kword] swizzled, whole K=256
    __shared__ float sd[64][17];       // dot partials
    __shared__ float scen[256];
    __shared__ float swl[256];
    __shared__ float dotf[64];

    int hwi = tid & 15, kc = tid >> 4; // thread: hw hwi*4..+3, channels {2kc,2kc+1}+32s

    // ---- issue ALL global loads up front: scen/swl first, then 16 x dwordx4 ----
    float cenv = ws[CEN_OFF + xb * 256 + tid];
    float wlv  = ws[WLAST_OFF + tid];
    const float* xst = xp + (size_t)(kc * 2) * 1024 + hw0 + hwi * 4;
    float4 xv[16];
    #pragma unroll
    for (int s = 0; s < 8; ++s) {
        xv[2 * s]     = *(const float4*)(xst + (size_t)(32 * s) * 1024);
        xv[2 * s + 1] = *(const float4*)(xst + (size_t)(32 * s + 1) * 1024);
    }
    __builtin_amdgcn_sched_barrier(0);             // pin: all loads issued before any use
    scen[tid] = cenv;
    swl[tid]  = wlv;
    __syncthreads();                               // scen/swl visible

    // ---- convert + LDS write + center-dot ----
    float dotp[4] = {0.f, 0.f, 0.f, 0.f};
    #pragma unroll
    for (int s = 0; s < 8; ++s) {
        float4 e = xv[2 * s], o4 = xv[2 * s + 1];
        int c = kc * 2 + 32 * s;
        float s0 = scen[c], s1 = scen[c + 1];
        dotp[0] += e.x * s0 + o4.x * s1;
        dotp[1] += e.y * s0 + o4.y * s1;
        dotp[2] += e.z * s0 + o4.z * s1;
        dotp[3] += e.w * s0 + o4.w * s1;
        int col = kc + 16 * s;
        float ee[4] = {e.x, e.y, e.z, e.w};
        float oo[4] = {o4.x, o4.y, o4.z, o4.w};
        #pragma unroll
        for (int j = 0; j < 4; ++j) {
            int jj = (hwi + j) & 3;                // rotate rows (write 2-way max)
            int hwr = hwi * 4 + jj;
            sx[hwr][col ^ swz(hwr)] = pkbf(ee[jj], oo[jj]);
        }
    }
    #pragma unroll
    for (int j = 0; j < 4; ++j) sd[hwi * 4 + j][kc] = dotp[j];
    __syncthreads();                               // B1: sx + sd ready

    if (tid < 64) {                                // wave 0 finalizes dot
        float ssum = 0.f;
        #pragma unroll
        for (int k2 = 0; k2 < 16; ++k2) ssum += sd[tid][k2];
        dotf[tid] = ssum * (1.0f / 256.0f);
    }

    // ---- MFMA: 16 K-steps, no barriers, A prefetch distance 2 ----
    f32x16 acc[2][2];                  // [it: o 32-sub][jt: hw 32-sub]
    #pragma unroll
    for (int i = 0; i < 2; ++i)
        #pragma unroll
        for (int j = 0; j < 2; ++j)
            #pragma unroll
            for (int e = 0; e < 16; ++e) acc[i][j][e] = 0.0f;

    auto loadA = [&](int S, int it) -> bf16x8 {
        return *(const bf16x8*)(wfrag + (size_t)((S * 8 + (w * 2 + it)) * 64 + l) * 8);
    };
    auto loadB = [&](int S, int jt) -> bf16x8 {
        int hwr = jt * 32 + lw;
        int colb = (S * 8 + q * 4) ^ swz(hwr);
        bf16x8 r; __builtin_memcpy(&r, &sx[hwr][colb], 16);
        return r;
    };

    bf16x8 A0[2], A1[2], A2[2];
    A0[0] = loadA(0, 0); A0[1] = loadA(0, 1);
    A1[0] = loadA(1, 0); A1[1] = loadA(1, 1);
    #pragma unroll
    for (int S = 0; S < 16; ++S) {
        bf16x8 b0 = loadB(S, 0);
        bf16x8 b1 = loadB(S, 1);
        if (S + 2 < 16) { A2[0] = loadA(S + 2, 0); A2[1] = loadA(S + 2, 1); }
        acc[0][0] = __builtin_amdgcn_mfma_f32_32x32x16_bf16(A0[0], b0, acc[0][0], 0, 0, 0);
        acc[0][1] = __builtin_amdgcn_mfma_f32_32x32x16_bf16(A0[0], b1, acc[0][1], 0, 0, 0);
        acc[1][0] = __builtin_amdgcn_mfma_f32_32x32x16_bf16(A0[1], b0, acc[1][0], 0, 0, 0);
        acc[1][1] = __builtin_amdgcn_mfma_f32_32x32x16_bf16(A0[1], b1, acc[1][1], 0, 0, 0);
        A0[0] = A1[0]; A0[1] = A1[1];
        A1[0] = A2[0]; A1[1] = A2[1];
    }
    __syncthreads();                               // B2: dotf ready, sx intact

    // ---- epilogue: z += wlast*dot; sigmoid; x from LDS (bf16); DPP reduce ----
    float dv0 = dotf[lw];
    float dv1 = dotf[32 + lw];
    #pragma unroll
    for (int it = 0; it < 2; ++it) {
        int ob = w * 64 + it * 32;
        #pragma unroll
        for (int r = 0; r < 16; ++r) {
            int row = (r & 3) + 8 * (r >> 2) + 4 * q;   // C/D layout (m74/m101)
            int o = ob + row;
            float wl = swl[o];
            float z0 = acc[it][0][r] + wl * dv0;
            float z1 = acc[it][1][r] + wl * dv1;
            float a0 = __builtin_amdgcn_rcpf(1.0f + __expf(-z0));
            float a1 = __builtin_amdgcn_rcpf(1.0f + __expf(-z1));
            // x[o][hw0 + jt*32 + lw] from the staged bf16 tile (no global traffic)
            int col = o >> 1;
            unsigned w0 = sx[lw][col ^ swz(lw)];
            unsigned w1 = sx[32 + lw][col ^ swz(32 + lw)];
            float xv0, xv1;
            if (o & 1) {
                xv0 = __builtin_bit_cast(float, w0 & 0xffff0000u);
                xv1 = __builtin_bit_cast(float, w1 & 0xffff0000u);
            } else {
                xv0 = __builtin_bit_cast(float, w0 << 16);
                xv1 = __builtin_bit_cast(float, w1 << 16);
            }
            float sA = red32(a0 + a1);
            float sX = red32(a0 * xv0 + a1 * xv1);
            if (lw == 31) {                             // lanes 31,63 hold sums
                atomicAdd(&accA[o], sA);
                atomicAdd(&accX[o], sX);
            }
        }
    }
}

// out[b,o] = accX0/(accA0+eps) + accX1/(accA1+eps)
__global__ void k_out(const float* __restrict__ ws, float* __restrict__ out) {
    int idx = blockIdx.x * 256 + threadIdx.x;     // b*256 + o
    int b = idx >> 8, o = idx & 255;
    float a0 = ws[ACCA_OFF + b * 256 + o];
    float p0 = ws[ACCX_OFF + b * 256 + o];
    float a1 = ws[ACCA_OFF + (64 + b) * 256 + o];
    float p1 = ws[ACCX_OFF + (64 + b) * 256 + o];
    out[idx] = p0 / (a0 + 1e-8f) + p1 / (a1 + 1e-8f);
}

extern "C" void kernel_launch(void* const* d_in, const int* in_sizes, int n_in,
                              void* d_out, int out_size, void* d_ws, size_t ws_size,
                              hipStream_t stream) {
    const float* x1     = (const float*)d_in[0];
    const float* x2     = (const float*)d_in[1];
    const float* conv_w = (const float*)d_in[2];
    // d_in[3..6] (caLayer params) are dead: softmax over a size-1 axis == 1.
    float* ws  = (float*)d_ws;
    float* out = (float*)d_out;

    k_init<<<384, 256, 0, stream>>>(x1, x2, conv_w, ws);
    k_main<<<dim3(16, 128), 256, 0, stream>>>(x1, x2, ws);
    k_out<<<64, 256, 0, stream>>>(ws, out);
}